// Round 1
// baseline (3265.331 us; speedup 1.0000x reference)
//
#include <hip/hip_runtime.h>
#include <math.h>

// Problem constants (fixed by the reference)
#define NROWS 32768
#define DIM   1024      // D == H == K == 1024

// ---------------------------------------------------------------------------
// Tiled fp32 GEMM with fused bias + activation epilogue.
// C[M,N] = act(A[M,K] @ B[K,N] + bias[N])
// BM=BN=128, BK=16, 256 threads, 8x8 micro-tile per thread.
// EPI: 0 = relu, 1 = sigmoid
// ---------------------------------------------------------------------------
template<int EPI>
__global__ __launch_bounds__(256)
void gemm_epi(const float* __restrict__ A, const float* __restrict__ B,
              const float* __restrict__ bias, float* __restrict__ C,
              int M, int K, int Nn) {
    constexpr int BM = 128, BN = 128, BK = 16;
    __shared__ float As[BK][BM];   // transposed A tile: As[k][m]
    __shared__ float Bs[BK][BN];   // Bs[k][n]

    const int tid = threadIdx.x;
    const int br  = blockIdx.y;    // row block (M/128)
    const int bc  = blockIdx.x;    // col block (N/128)
    const int tr  = tid >> 4;      // 0..15 -> rows tr*8..tr*8+7
    const int tc  = tid & 15;      // 0..15 -> cols tc*8..tc*8+7

    float acc[8][8];
#pragma unroll
    for (int i = 0; i < 8; ++i)
#pragma unroll
        for (int j = 0; j < 8; ++j) acc[i][j] = 0.f;

    // staging assignments
    const int arow = tid >> 1;          // 0..127
    const int acol = (tid & 1) * 8;     // 0 or 8
    const int brow = tid >> 4;          // 0..15
    const int bcol = (tid & 15) * 8;    // 0..120

    const float* Ab = A + (size_t)(br * BM + arow) * K + acol;
    const float* Bb = B + (size_t)brow * Nn + (size_t)bc * BN + bcol;

    for (int k0 = 0; k0 < K; k0 += BK) {
        // global -> regs
        const float4 a0 = *(const float4*)(Ab + k0);
        const float4 a1 = *(const float4*)(Ab + k0 + 4);
        const float4 b0 = *(const float4*)(Bb + (size_t)k0 * Nn);
        const float4 b1 = *(const float4*)(Bb + (size_t)k0 * Nn + 4);

        __syncthreads();   // all threads done reading LDS from prev iter
        As[acol + 0][arow] = a0.x; As[acol + 1][arow] = a0.y;
        As[acol + 2][arow] = a0.z; As[acol + 3][arow] = a0.w;
        As[acol + 4][arow] = a1.x; As[acol + 5][arow] = a1.y;
        As[acol + 6][arow] = a1.z; As[acol + 7][arow] = a1.w;
        *(float4*)&Bs[brow][bcol]     = b0;
        *(float4*)&Bs[brow][bcol + 4] = b1;
        __syncthreads();

#pragma unroll
        for (int kk = 0; kk < BK; ++kk) {
            const float4 av0 = *(const float4*)&As[kk][tr * 8];
            const float4 av1 = *(const float4*)&As[kk][tr * 8 + 4];
            const float4 bv0 = *(const float4*)&Bs[kk][tc * 8];
            const float4 bv1 = *(const float4*)&Bs[kk][tc * 8 + 4];
            const float av[8] = {av0.x, av0.y, av0.z, av0.w, av1.x, av1.y, av1.z, av1.w};
            const float bv[8] = {bv0.x, bv0.y, bv0.z, bv0.w, bv1.x, bv1.y, bv1.z, bv1.w};
#pragma unroll
            for (int i = 0; i < 8; ++i)
#pragma unroll
                for (int j = 0; j < 8; ++j)
                    acc[i][j] += av[i] * bv[j];
        }
    }

    // epilogue
    const int crow0 = br * BM + tr * 8;
    const int ccol0 = bc * BN + tc * 8;
#pragma unroll
    for (int i = 0; i < 8; ++i) {
        float o[8];
#pragma unroll
        for (int j = 0; j < 8; ++j) {
            float v = acc[i][j] + bias[ccol0 + j];
            if (EPI == 0) {
                v = fmaxf(v, 0.f);
            } else {
                v = 1.0f / (1.0f + expf(-v));
            }
            o[j] = v;
        }
        float* Crow = C + (size_t)(crow0 + i) * Nn + ccol0;
        *(float4*)(Crow)     = make_float4(o[0], o[1], o[2], o[3]);
        *(float4*)(Crow + 4) = make_float4(o[4], o[5], o[6], o[7]);
    }
}

// ---------------------------------------------------------------------------
// Codebook row sums: S[i] = sum_j C[i,j], Q[i] = sum_j C[i,j]^2  (fp64 accum)
// One block (256 threads) per codebook row.
// ---------------------------------------------------------------------------
__global__ __launch_bounds__(256)
void cb_stats(const float* __restrict__ CB, float* __restrict__ S, float* __restrict__ Q) {
    const int i = blockIdx.x;
    const float* row = CB + (size_t)i * DIM;
    double s = 0.0, q = 0.0;
    for (int j = threadIdx.x; j < DIM; j += 256) {
        const double v = (double)row[j];
        s += v;
        q += v * v;
    }
    // wave reduce (64 lanes)
#pragma unroll
    for (int off = 32; off; off >>= 1) {
        s += __shfl_down(s, off);
        q += __shfl_down(q, off);
    }
    __shared__ double sS[4], sQ[4];
    const int wid = threadIdx.x >> 6;
    if ((threadIdx.x & 63) == 0) { sS[wid] = s; sQ[wid] = q; }
    __syncthreads();
    if (threadIdx.x == 0) {
        for (int w = 1; w < 4; ++w) { s += sS[w]; q += sQ[w]; }
        S[i] = (float)s;
        Q[i] = (float)q;
    }
}

// ---------------------------------------------------------------------------
// VQ: per row n, idx = first-argmin_i( 1024*z_i^2 - 2*z_i*S_i + Q_i ),
// then z_q[n,:] = codebook[idx,:].  One block (256 threads) per row.
// Replicates numpy's fp32 op order (no FMA contraction) and first-index
// tie-break of np.argmin.
// ---------------------------------------------------------------------------
__global__ __launch_bounds__(256)
void vq_argmin_gather(const float* __restrict__ z_e,
                      const float* __restrict__ S, const float* __restrict__ Q,
                      const float* __restrict__ CB, float* __restrict__ z_q) {
    const int n = blockIdx.x;
    const float* z = z_e + (size_t)n * DIM;
    const int tid = threadIdx.x;

    float best = 3.4e38f;
    int   bi   = 0x7fffffff;
    for (int i = tid; i < DIM; i += 256) {
        const float zv = z[i];
        // ((1024*(z*z)) - ((2*z)*S)) + Q, each step rounded like np fp32
        const float t  = __fmul_rn(zv, zv);
        const float a  = __fmul_rn(1024.0f, t);         // exact scale by 2^10
        const float b  = __fmul_rn(__fmul_rn(2.0f, zv), S[i]);
        const float d  = __fadd_rn(__fsub_rn(a, b), Q[i]);
        if (d < best) { best = d; bi = i; }   // strict <  => first occurrence
    }
    // wave reduce with (value, index) first-min combine
#pragma unroll
    for (int off = 32; off; off >>= 1) {
        const float od = __shfl_down(best, off);
        const int   oi = __shfl_down(bi,   off);
        if (od < best || (od == best && oi < bi)) { best = od; bi = oi; }
    }
    __shared__ float sd[4];
    __shared__ int   si[4];
    const int wid = tid >> 6;
    if ((tid & 63) == 0) { sd[wid] = best; si[wid] = bi; }
    __syncthreads();
    if (tid == 0) {
        for (int w = 1; w < 4; ++w)
            if (sd[w] < best || (sd[w] == best && si[w] < bi)) { best = sd[w]; bi = si[w]; }
        si[0] = bi;
    }
    __syncthreads();
    bi = si[0];

    // gather codebook row -> z_q row (256 threads x float4 = 1024 floats)
    const float4* src = (const float4*)(CB + (size_t)bi * DIM);
    float4* dst = (float4*)(z_q + (size_t)n * DIM);
    dst[tid] = src[tid];
}

// ---------------------------------------------------------------------------
extern "C" void kernel_launch(void* const* d_in, const int* in_sizes, int n_in,
                              void* d_out, int out_size, void* d_ws, size_t ws_size,
                              hipStream_t stream) {
    const float* x  = (const float*)d_in[0];
    const float* W1 = (const float*)d_in[1];
    const float* b1 = (const float*)d_in[2];
    const float* W2 = (const float*)d_in[3];
    const float* b2 = (const float*)d_in[4];
    const float* CB = (const float*)d_in[5];
    const float* W3 = (const float*)d_in[6];
    const float* b3 = (const float*)d_in[7];
    const float* W4 = (const float*)d_in[8];
    const float* b4 = (const float*)d_in[9];

    float* out     = (float*)d_out;
    float* x_recon = out;                              // region 0 (N*DIM)
    float* z_e     = out + (size_t)NROWS * DIM;        // region 1
    float* z_q     = out + (size_t)2 * NROWS * DIM;    // region 2

    // h1 temporarily lives in the x_recon slot (GEMM4 overwrites it last).
    float* h1 = x_recon;
    // h3 (N*DIM fp32) + S,Q (2*DIM) in workspace: 128 MB + 8 KB.
    float* h3 = (float*)d_ws;
    float* S  = h3 + (size_t)NROWS * DIM;
    float* Q  = S + DIM;

    const dim3 blk(256);
    const dim3 grid_gemm(DIM / 128, NROWS / 128);      // (8, 256)

    // encoder (fp32 — argmin fidelity requires it)
    gemm_epi<0><<<grid_gemm, blk, 0, stream>>>(x,  W1, b1, h1,  NROWS, DIM, DIM);
    gemm_epi<0><<<grid_gemm, blk, 0, stream>>>(h1, W2, b2, z_e, NROWS, DIM, DIM);

    // VQ
    cb_stats<<<dim3(DIM), blk, 0, stream>>>(CB, S, Q);
    vq_argmin_gather<<<dim3(NROWS), blk, 0, stream>>>(z_e, S, Q, CB, z_q);

    // decoder
    gemm_epi<0><<<grid_gemm, blk, 0, stream>>>(z_q, W3, b3, h3,      NROWS, DIM, DIM);
    gemm_epi<1><<<grid_gemm, blk, 0, stream>>>(h3,  W4, b4, x_recon, NROWS, DIM, DIM);
}

// Round 2
// 2173.707 us; speedup vs baseline: 1.5022x; 1.5022x over previous
//
#include <hip/hip_runtime.h>
#include <hip/hip_bf16.h>
#include <math.h>

// Problem constants (fixed by the reference)
#define NROWS 32768
#define DIM   1024      // D == H == K == 1024

typedef __attribute__((ext_vector_type(8))) short bf16x8;   // 8 bf16 (4 VGPRs)
typedef __attribute__((ext_vector_type(4))) float f32x4;    // MFMA accumulator

__device__ __forceinline__ ushort f2bf(float f) {
    union { float f; unsigned u; } a; a.f = f;
    unsigned r = a.u + 0x7fff + ((a.u >> 16) & 1);   // RNE
    return (ushort)(r >> 16);
}

__device__ __forceinline__ void async_copy16(void* lds, const void* g) {
    __builtin_amdgcn_global_load_lds(
        (const __attribute__((address_space(1))) void*)g,
        (__attribute__((address_space(3))) void*)lds,
        16, 0, 0);
}

// ---------------------------------------------------------------------------
// fp32 VALU GEMM with fused bias+relu (encoder only; argmin fidelity).
// ---------------------------------------------------------------------------
template<int EPI>
__global__ __launch_bounds__(256)
void gemm_epi(const float* __restrict__ A, const float* __restrict__ B,
              const float* __restrict__ bias, float* __restrict__ C,
              int M, int K, int Nn) {
    constexpr int BM = 128, BN = 128, BK = 16;
    __shared__ float As[BK][BM];
    __shared__ float Bs[BK][BN];

    const int tid = threadIdx.x;
    const int br  = blockIdx.y;
    const int bc  = blockIdx.x;
    const int tr  = tid >> 4;
    const int tc  = tid & 15;

    float acc[8][8];
#pragma unroll
    for (int i = 0; i < 8; ++i)
#pragma unroll
        for (int j = 0; j < 8; ++j) acc[i][j] = 0.f;

    const int arow = tid >> 1;
    const int acol = (tid & 1) * 8;
    const int brow = tid >> 4;
    const int bcol = (tid & 15) * 8;

    const float* Ab = A + (size_t)(br * BM + arow) * K + acol;
    const float* Bb = B + (size_t)brow * Nn + (size_t)bc * BN + bcol;

    for (int k0 = 0; k0 < K; k0 += BK) {
        const float4 a0 = *(const float4*)(Ab + k0);
        const float4 a1 = *(const float4*)(Ab + k0 + 4);
        const float4 b0 = *(const float4*)(Bb + (size_t)k0 * Nn);
        const float4 b1 = *(const float4*)(Bb + (size_t)k0 * Nn + 4);

        __syncthreads();
        As[acol + 0][arow] = a0.x; As[acol + 1][arow] = a0.y;
        As[acol + 2][arow] = a0.z; As[acol + 3][arow] = a0.w;
        As[acol + 4][arow] = a1.x; As[acol + 5][arow] = a1.y;
        As[acol + 6][arow] = a1.z; As[acol + 7][arow] = a1.w;
        *(float4*)&Bs[brow][bcol]     = b0;
        *(float4*)&Bs[brow][bcol + 4] = b1;
        __syncthreads();

#pragma unroll
        for (int kk = 0; kk < BK; ++kk) {
            const float4 av0 = *(const float4*)&As[kk][tr * 8];
            const float4 av1 = *(const float4*)&As[kk][tr * 8 + 4];
            const float4 bv0 = *(const float4*)&Bs[kk][tc * 8];
            const float4 bv1 = *(const float4*)&Bs[kk][tc * 8 + 4];
            const float av[8] = {av0.x, av0.y, av0.z, av0.w, av1.x, av1.y, av1.z, av1.w};
            const float bv[8] = {bv0.x, bv0.y, bv0.z, bv0.w, bv1.x, bv1.y, bv1.z, bv1.w};
#pragma unroll
            for (int i = 0; i < 8; ++i)
#pragma unroll
                for (int j = 0; j < 8; ++j)
                    acc[i][j] += av[i] * bv[j];
        }
    }

    const int crow0 = br * BM + tr * 8;
    const int ccol0 = bc * BN + tc * 8;
#pragma unroll
    for (int i = 0; i < 8; ++i) {
        float o[8];
#pragma unroll
        for (int j = 0; j < 8; ++j) {
            float v = acc[i][j] + bias[ccol0 + j];
            v = fmaxf(v, 0.f);
            o[j] = v;
        }
        float* Crow = C + (size_t)(crow0 + i) * Nn + ccol0;
        *(float4*)(Crow)     = make_float4(o[0], o[1], o[2], o[3]);
        *(float4*)(Crow + 4) = make_float4(o[4], o[5], o[6], o[7]);
    }
}

// ---------------------------------------------------------------------------
// bf16 MFMA GEMM: C = epi(A @ Bt^T + bias), Bt is [N][K] bf16 (pre-transposed).
// m97 structure: 128x128 tile, BK=32, 4 waves (2x2) x (4x4) 16x16x32 frags.
// APATH 0: A is [M][K] bf16, staged via global_load_lds.
// APATH 1: A row m = CBb[idx[m]], reg-staged (codebook-indexed gather GEMM).
// EPI 0: relu -> bf16 out.  EPI 1: sigmoid -> fp32 out.
// Grid: 1D, (M/128)*(N/128) blocks; requires N==1024 (8 col blocks), M/128 % 8 == 0.
// ---------------------------------------------------------------------------
template<int EPI, int APATH>
__global__ __launch_bounds__(256)
void gemm_mfma(const ushort* __restrict__ A, const ushort* __restrict__ CBb,
               const int* __restrict__ idx, const ushort* __restrict__ Bt,
               const float* __restrict__ bias, void* __restrict__ Cout,
               int M, int K, int N) {
    constexpr int BM = 128, BN = 128, BK = 32;
    __shared__ ushort As[BM][BK];   // [row][k]
    __shared__ ushort Bs[BN][BK];   // [col][k]

    // XCD-aware swizzle: cluster the 8 col-blocks sharing an A panel on one XCD,
    // back-to-back in time. Bijective for gridDim = 8*(M/128), M/128 % 8 == 0.
    const int hw = blockIdx.x;
    const int x  = hw & 7, j = hw >> 3;
    const int bc = j & 7, br = (j >> 3) * 8 + x;
    const int row0 = br * BM, col0 = bc * BN;

    const int tid  = threadIdx.x;
    const int lane = tid & 63, wid = tid >> 6;
    const int wr = (wid >> 1) * 64, wc = (wid & 1) * 64;   // wave tile origin
    const int lr = lane & 15, lg = lane >> 4;              // frag row/col, k-group

    f32x4 acc[4][4] = {};

    // staging: 512 chunks of 16B per tile; thread t handles chunks t and t+256.
    // chunk c: row = c>>2, k-offset = (c&3)*8 elements.
    const int r0   = tid >> 2;
    const int koff = (tid & 3) * 8;

    const ushort* Bg0 = Bt + (size_t)(col0 + r0) * K + koff;
    const ushort* Bg1 = Bt + (size_t)(col0 + 64 + r0) * K + koff;
    ushort* lA0 = &As[r0][koff];
    ushort* lA1 = &As[64 + r0][koff];
    ushort* lB0 = &Bs[r0][koff];
    ushort* lB1 = &Bs[64 + r0][koff];

    const ushort* Ag0;
    const ushort* Ag1;
    if (APATH == 0) {
        Ag0 = A + (size_t)(row0 + r0) * K + koff;
        Ag1 = A + (size_t)(row0 + 64 + r0) * K + koff;
    } else {
        Ag0 = CBb + (size_t)idx[row0 + r0] * K + koff;
        Ag1 = CBb + (size_t)idx[row0 + 64 + r0] * K + koff;
    }

    for (int k0 = 0; k0 < K; k0 += BK) {
        if (APATH == 0) {
            async_copy16(lA0, Ag0 + k0);
            async_copy16(lA1, Ag1 + k0);
            async_copy16(lB0, Bg0 + k0);
            async_copy16(lB1, Bg1 + k0);
        } else {
            const int4 ra0 = *(const int4*)(Ag0 + k0);
            const int4 ra1 = *(const int4*)(Ag1 + k0);
            async_copy16(lB0, Bg0 + k0);
            async_copy16(lB1, Bg1 + k0);
            *(int4*)lA0 = ra0;
            *(int4*)lA1 = ra1;
        }
        __syncthreads();   // drains vmcnt+lgkm, tiles visible

        bf16x8 av[4], bv[4];
#pragma unroll
        for (int m = 0; m < 4; ++m)
            av[m] = *(const bf16x8*)&As[wr + m * 16 + lr][lg * 8];
#pragma unroll
        for (int n = 0; n < 4; ++n)
            bv[n] = *(const bf16x8*)&Bs[wc + n * 16 + lr][lg * 8];
#pragma unroll
        for (int m = 0; m < 4; ++m)
#pragma unroll
            for (int n = 0; n < 4; ++n)
                acc[m][n] = __builtin_amdgcn_mfma_f32_16x16x32_bf16(
                    av[m], bv[n], acc[m][n], 0, 0, 0);
        __syncthreads();   // all reads done before next overwrite
    }

    // epilogue: C/D layout col=lane&15, row=(lane>>4)*4+reg  [m89/m91 verified]
    float bvals[4];
#pragma unroll
    for (int n = 0; n < 4; ++n) bvals[n] = bias[col0 + wc + n * 16 + lr];

#pragma unroll
    for (int m = 0; m < 4; ++m) {
#pragma unroll
        for (int jj = 0; jj < 4; ++jj) {
            const size_t grow = row0 + wr + m * 16 + lg * 4 + jj;
#pragma unroll
            for (int n = 0; n < 4; ++n) {
                const int gcol = col0 + wc + n * 16 + lr;
                float v = acc[m][n][jj] + bvals[n];
                if (EPI == 0) {
                    v = fmaxf(v, 0.f);
                    ((ushort*)Cout)[grow * N + gcol] = f2bf(v);
                } else {
                    v = 1.0f / (1.0f + expf(-v));
                    ((float*)Cout)[grow * N + gcol] = v;
                }
            }
        }
    }
}

// ---------------------------------------------------------------------------
// Transpose + convert: Wt[n][k] = bf16(W[k][n]).  32x32 tiles, block 256.
// ---------------------------------------------------------------------------
__global__ __launch_bounds__(256)
void wt_convert(const float* __restrict__ W, ushort* __restrict__ Wt) {
    __shared__ float t[32][33];
    const int bi = blockIdx.y;   // k block
    const int bj = blockIdx.x;   // n block
    const int tx = threadIdx.x & 31, ty = threadIdx.x >> 5;   // 32 x 8
#pragma unroll
    for (int r = 0; r < 4; ++r)
        t[ty + r * 8][tx] = W[(size_t)(bi * 32 + ty + r * 8) * DIM + bj * 32 + tx];
    __syncthreads();
#pragma unroll
    for (int r = 0; r < 4; ++r)
        Wt[(size_t)(bj * 32 + ty + r * 8) * DIM + bi * 32 + tx] = f2bf(t[tx][ty + r * 8]);
}

// ---------------------------------------------------------------------------
// Codebook stats + bf16 convert: S[i]=sum_j C[i,j], Q[i]=sum_j C[i,j]^2 (fp64),
// CBb[i][j] = bf16(C[i][j]).  One block per row.
// ---------------------------------------------------------------------------
__global__ __launch_bounds__(256)
void cb_stats(const float* __restrict__ CB, float* __restrict__ S,
              float* __restrict__ Q, ushort* __restrict__ CBb) {
    const int i = blockIdx.x;
    const float* row = CB + (size_t)i * DIM;
    double s = 0.0, q = 0.0;
    for (int j = threadIdx.x; j < DIM; j += 256) {
        const float fv = row[j];
        CBb[(size_t)i * DIM + j] = f2bf(fv);
        const double v = (double)fv;
        s += v;
        q += v * v;
    }
#pragma unroll
    for (int off = 32; off; off >>= 1) {
        s += __shfl_down(s, off);
        q += __shfl_down(q, off);
    }
    __shared__ double sS[4], sQ[4];
    const int wid = threadIdx.x >> 6;
    if ((threadIdx.x & 63) == 0) { sS[wid] = s; sQ[wid] = q; }
    __syncthreads();
    if (threadIdx.x == 0) {
        for (int w = 1; w < 4; ++w) { s += sS[w]; q += sQ[w]; }
        S[i] = (float)s;
        Q[i] = (float)q;
    }
}

// ---------------------------------------------------------------------------
// VQ argmin (numpy-exact fp32 op order, first-index tie-break) + fp32 gather.
// Writes idx for the downstream codebook-indexed GEMM.
// ---------------------------------------------------------------------------
__global__ __launch_bounds__(256)
void vq_argmin_gather(const float* __restrict__ z_e,
                      const float* __restrict__ S, const float* __restrict__ Q,
                      const float* __restrict__ CB, float* __restrict__ z_q,
                      int* __restrict__ idxp) {
    const int n = blockIdx.x;
    const float* z = z_e + (size_t)n * DIM;
    const int tid = threadIdx.x;

    float best = 3.4e38f;
    int   bi   = 0x7fffffff;
    for (int i = tid; i < DIM; i += 256) {
        const float zv = z[i];
        const float t  = __fmul_rn(zv, zv);
        const float a  = __fmul_rn(1024.0f, t);
        const float b  = __fmul_rn(__fmul_rn(2.0f, zv), S[i]);
        const float d  = __fadd_rn(__fsub_rn(a, b), Q[i]);
        if (d < best) { best = d; bi = i; }
    }
#pragma unroll
    for (int off = 32; off; off >>= 1) {
        const float od = __shfl_down(best, off);
        const int   oi = __shfl_down(bi,   off);
        if (od < best || (od == best && oi < bi)) { best = od; bi = oi; }
    }
    __shared__ float sd[4];
    __shared__ int   si[4];
    const int wid = tid >> 6;
    if ((tid & 63) == 0) { sd[wid] = best; si[wid] = bi; }
    __syncthreads();
    if (tid == 0) {
        for (int w = 1; w < 4; ++w)
            if (sd[w] < best || (sd[w] == best && si[w] < bi)) { best = sd[w]; bi = si[w]; }
        si[0] = bi;
    }
    __syncthreads();
    bi = si[0];
    if (tid == 0) idxp[n] = bi;

    const float4* src = (const float4*)(CB + (size_t)bi * DIM);
    float4* dst = (float4*)(z_q + (size_t)n * DIM);
    dst[tid] = src[tid];
}

// ---------------------------------------------------------------------------
extern "C" void kernel_launch(void* const* d_in, const int* in_sizes, int n_in,
                              void* d_out, int out_size, void* d_ws, size_t ws_size,
                              hipStream_t stream) {
    const float* x  = (const float*)d_in[0];
    const float* W1 = (const float*)d_in[1];
    const float* b1 = (const float*)d_in[2];
    const float* W2 = (const float*)d_in[3];
    const float* b2 = (const float*)d_in[4];
    const float* CB = (const float*)d_in[5];
    const float* W3 = (const float*)d_in[6];
    const float* b3 = (const float*)d_in[7];
    const float* W4 = (const float*)d_in[8];
    const float* b4 = (const float*)d_in[9];

    float* out     = (float*)d_out;
    float* x_recon = out;                              // region 0
    float* z_e     = out + (size_t)NROWS * DIM;        // region 1
    float* z_q     = out + (size_t)2 * NROWS * DIM;    // region 2

    float* h1 = x_recon;   // fp32 scratch in x_recon slot (overwritten by GEMM4 last)

    // workspace layout (bytes):
    //   0         h3 bf16  (NROWS*DIM*2 = 67,108,864)
    //   67108864  CBb bf16 (2 MB)
    //   69206016  W3t bf16 (2 MB)
    //   71303168  W4t bf16 (2 MB)
    //   73400320  S (4 KB) | 73404416 Q (4 KB) | 73408512 idx (128 KB)
    char* wsb = (char*)d_ws;
    ushort* h3b = (ushort*)(wsb);
    ushort* CBb = (ushort*)(wsb + 67108864);
    ushort* W3t = (ushort*)(wsb + 69206016);
    ushort* W4t = (ushort*)(wsb + 71303168);
    float*  S   = (float*)(wsb + 73400320);
    float*  Q   = (float*)(wsb + 73404416);
    int*    idx = (int*)(wsb + 73408512);

    const dim3 blk(256);
    const dim3 grid_gemm32(DIM / 128, NROWS / 128);    // (8, 256) fp32 encoder
    const dim3 grid_mfma((NROWS / 128) * (DIM / 128)); // 2048, 1D (swizzled)
    const dim3 grid_tr(32, 32);

    // prep (independent of encoder)
    wt_convert<<<grid_tr, blk, 0, stream>>>(W3, W3t);
    wt_convert<<<grid_tr, blk, 0, stream>>>(W4, W4t);
    cb_stats<<<dim3(DIM), blk, 0, stream>>>(CB, S, Q, CBb);

    // encoder (fp32 — argmin fidelity requires it)
    gemm_epi<0><<<grid_gemm32, blk, 0, stream>>>(x,  W1, b1, h1,  NROWS, DIM, DIM);
    gemm_epi<0><<<grid_gemm32, blk, 0, stream>>>(h1, W2, b2, z_e, NROWS, DIM, DIM);

    // VQ
    vq_argmin_gather<<<dim3(NROWS), blk, 0, stream>>>(z_e, S, Q, CB, z_q, idx);

    // decoder (bf16 MFMA)
    gemm_mfma<0, 1><<<grid_mfma, blk, 0, stream>>>(
        (const ushort*)nullptr, CBb, idx, W3t, b3, (void*)h3b, NROWS, DIM, DIM);
    gemm_mfma<1, 0><<<grid_mfma, blk, 0, stream>>>(
        h3b, (const ushort*)nullptr, (const int*)nullptr, W4t, b4, (void*)x_recon,
        NROWS, DIM, DIM);
}

// Round 4
// 1540.408 us; speedup vs baseline: 2.1198x; 1.4111x over previous
//
#include <hip/hip_runtime.h>
#include <hip/hip_bf16.h>
#include <math.h>

// Problem constants (fixed by the reference)
#define NROWS 32768
#define HALF  16384
#define DIM   1024      // D == H == K == 1024

typedef __attribute__((ext_vector_type(8))) short bf16x8;     // 8 bf16 (4 VGPRs)
typedef _Float16 f16x8 __attribute__((ext_vector_type(8)));   // 8 fp16 (4 VGPRs)
typedef __attribute__((ext_vector_type(4))) float f32x4;      // MFMA accumulator

__device__ __forceinline__ ushort f2bf(float f) {
    union { float f; unsigned u; } a; a.f = f;
    unsigned r = a.u + 0x7fff + ((a.u >> 16) & 1);   // RNE
    return (ushort)(r >> 16);
}
__device__ __forceinline__ ushort f2h(float f) {
    union { _Float16 h; ushort u; } c; c.h = (_Float16)f; return c.u;
}
__device__ __forceinline__ float h2f(ushort u) {
    union { ushort u; _Float16 h; } c; c.u = u; return (float)c.h;
}

__device__ __forceinline__ void async_copy16(void* lds, const void* g) {
    __builtin_amdgcn_global_load_lds(
        (const __attribute__((address_space(1))) void*)g,
        (__attribute__((address_space(3))) void*)lds,
        16, 0, 0);
}

// split 8 fp32 -> fp16 main + fp16 residual*4096
__device__ __forceinline__ void split8(const float4 lo, const float4 hi,
                                       f16x8& a, f16x8& b) {
    const float v[8] = {lo.x, lo.y, lo.z, lo.w, hi.x, hi.y, hi.z, hi.w};
#pragma unroll
    for (int i = 0; i < 8; ++i) {
        const _Float16 ha = (_Float16)v[i];
        a[i] = ha;
        b[i] = (_Float16)((v[i] - (float)ha) * 4096.f);
    }
}

// ---------------------------------------------------------------------------
// Transpose + fp16x2 split: Wta[n][k] = f16(W[k][n]), Wtb = f16(resid*4096).
// ---------------------------------------------------------------------------
__global__ __launch_bounds__(256)
void split_wt(const float* __restrict__ W, ushort* __restrict__ Wta,
              ushort* __restrict__ Wtb) {
    __shared__ float t[32][33];
    const int bi = blockIdx.y;   // k block
    const int bj = blockIdx.x;   // n block
    const int tx = threadIdx.x & 31, ty = threadIdx.x >> 5;   // 32 x 8
#pragma unroll
    for (int r = 0; r < 4; ++r)
        t[ty + r * 8][tx] = W[(size_t)(bi * 32 + ty + r * 8) * DIM + bj * 32 + tx];
    __syncthreads();
#pragma unroll
    for (int r = 0; r < 4; ++r) {
        const float v = t[tx][ty + r * 8];
        const ushort a = f2h(v);
        const size_t o = (size_t)(bj * 32 + ty + r * 8) * DIM + bi * 32 + tx;
        Wta[o] = a;
        Wtb[o] = f2h((v - h2f(a)) * 4096.f);
    }
}

// ---------------------------------------------------------------------------
// Transpose + convert to bf16 (decoder weights): Wt[n][k] = bf16(W[k][n]).
// ---------------------------------------------------------------------------
__global__ __launch_bounds__(256)
void wt_convert(const float* __restrict__ W, ushort* __restrict__ Wt) {
    __shared__ float t[32][33];
    const int bi = blockIdx.y;
    const int bj = blockIdx.x;
    const int tx = threadIdx.x & 31, ty = threadIdx.x >> 5;
#pragma unroll
    for (int r = 0; r < 4; ++r)
        t[ty + r * 8][tx] = W[(size_t)(bi * 32 + ty + r * 8) * DIM + bj * 32 + tx];
    __syncthreads();
#pragma unroll
    for (int r = 0; r < 4; ++r)
        Wt[(size_t)(bj * 32 + ty + r * 8) * DIM + bi * 32 + tx] = f2bf(t[tx][ty + r * 8]);
}

// ---------------------------------------------------------------------------
// fp16x2 split MFMA GEMM (encoder): C = relu(A @ Bt^T + bias), fp32-accurate.
// A = Aa + Ab/4096, B = Ba + Bb/4096 ([N][K] fp16 pairs in ws).
// acc += Aa*Ba ; accc += Aa*Bb + Ab*Ba ; C = acc + accc/4096 + bias.
// APATH 0: A is fp32 [M][K] (read from d_in), split in-register during staging.
// APATH 1: A is fp16 pair [M][K] (ws), staged via global_load_lds.
// EPI 0: relu -> fp16 pair out (Ca fp16 main, Cb fp16 resid).
// EPI 1: relu -> fp32 out (Ca).
// 128x128 tile, BK=32, 4 waves (2x2) x (4x4) 16x16x32 frags (round-2 skeleton).
// ---------------------------------------------------------------------------
template<int APATH, int EPI>
__global__ __launch_bounds__(256)
void gemm_f16x2(const float* __restrict__ Af,
                const ushort* __restrict__ Aa, const ushort* __restrict__ Ab,
                const ushort* __restrict__ Ba, const ushort* __restrict__ Bb,
                const float* __restrict__ bias, void* __restrict__ Ca,
                ushort* __restrict__ Cb, int M, int K, int N) {
    constexpr int BM = 128, BN = 128, BK = 32;
    __shared__ ushort Asa[BM][BK];
    __shared__ ushort Asb[BM][BK];
    __shared__ ushort Bsa[BN][BK];
    __shared__ ushort Bsb[BN][BK];

    // XCD-aware swizzle (bijective: gridDim = 8*(M/128), M/128 % 8 == 0)
    const int hw = blockIdx.x;
    const int x  = hw & 7, j = hw >> 3;
    const int bc = j & 7, br = (j >> 3) * 8 + x;
    const int row0 = br * BM, col0 = bc * BN;

    const int tid  = threadIdx.x;
    const int lane = tid & 63, wid = tid >> 6;
    const int wr = (wid >> 1) * 64, wc = (wid & 1) * 64;
    const int lr = lane & 15, lg = lane >> 4;

    f32x4 acc[4][4]  = {};
    f32x4 accc[4][4] = {};

    const int r0 = tid >> 2;           // 0..63
    const int kq = (tid & 3) * 8;      // k-element offset: 0,8,16,24

    // B operands (always fp16 pair in ws, linear global_load_lds)
    const ushort* Bga0 = Ba + (size_t)(col0 + r0) * K + kq;
    const ushort* Bga1 = Ba + (size_t)(col0 + 64 + r0) * K + kq;
    const ushort* Bgb0 = Bb + (size_t)(col0 + r0) * K + kq;
    const ushort* Bgb1 = Bb + (size_t)(col0 + 64 + r0) * K + kq;
    ushort* lBa0 = &Bsa[r0][kq];      ushort* lBa1 = &Bsa[64 + r0][kq];
    ushort* lBb0 = &Bsb[r0][kq];      ushort* lBb1 = &Bsb[64 + r0][kq];

    // A operand pointers
    const float*  Af0 = nullptr; const float*  Af1 = nullptr;
    const ushort* Aga0 = nullptr; const ushort* Aga1 = nullptr;
    const ushort* Agb0 = nullptr; const ushort* Agb1 = nullptr;
    if (APATH == 0) {
        Af0 = Af + (size_t)(row0 + r0) * K + kq;
        Af1 = Af + (size_t)(row0 + 64 + r0) * K + kq;
    } else {
        Aga0 = Aa + (size_t)(row0 + r0) * K + kq;
        Aga1 = Aa + (size_t)(row0 + 64 + r0) * K + kq;
        Agb0 = Ab + (size_t)(row0 + r0) * K + kq;
        Agb1 = Ab + (size_t)(row0 + 64 + r0) * K + kq;
    }
    ushort* lAa0 = &Asa[r0][kq];      ushort* lAa1 = &Asa[64 + r0][kq];
    ushort* lAb0 = &Asb[r0][kq];      ushort* lAb1 = &Asb[64 + r0][kq];

    for (int k0 = 0; k0 < K; k0 += BK) {
        if (APATH == 0) {
            // fp32 loads first (latency), then async B copies, then split+ds_write
            const float4 f00 = *(const float4*)(Af0 + k0);
            const float4 f01 = *(const float4*)(Af0 + k0 + 4);
            const float4 f10 = *(const float4*)(Af1 + k0);
            const float4 f11 = *(const float4*)(Af1 + k0 + 4);
            async_copy16(lBa0, Bga0 + k0);
            async_copy16(lBa1, Bga1 + k0);
            async_copy16(lBb0, Bgb0 + k0);
            async_copy16(lBb1, Bgb1 + k0);
            f16x8 a0, b0, a1, b1;
            split8(f00, f01, a0, b0);
            split8(f10, f11, a1, b1);
            *(f16x8*)lAa0 = a0;
            *(f16x8*)lAb0 = b0;
            *(f16x8*)lAa1 = a1;
            *(f16x8*)lAb1 = b1;
        } else {
            async_copy16(lAa0, Aga0 + k0);
            async_copy16(lAa1, Aga1 + k0);
            async_copy16(lAb0, Agb0 + k0);
            async_copy16(lAb1, Agb1 + k0);
            async_copy16(lBa0, Bga0 + k0);
            async_copy16(lBa1, Bga1 + k0);
            async_copy16(lBb0, Bgb0 + k0);
            async_copy16(lBb1, Bgb1 + k0);
        }
        __syncthreads();   // drains vmcnt+lgkm; tiles visible to all waves

        f16x8 a1f[4], a2f[4], b1f[4], b2f[4];
#pragma unroll
        for (int m = 0; m < 4; ++m) {
            a1f[m] = *(const f16x8*)&Asa[wr + m * 16 + lr][lg * 8];
            a2f[m] = *(const f16x8*)&Asb[wr + m * 16 + lr][lg * 8];
        }
#pragma unroll
        for (int n = 0; n < 4; ++n) {
            b1f[n] = *(const f16x8*)&Bsa[wc + n * 16 + lr][lg * 8];
            b2f[n] = *(const f16x8*)&Bsb[wc + n * 16 + lr][lg * 8];
        }
#pragma unroll
        for (int m = 0; m < 4; ++m)
#pragma unroll
            for (int n = 0; n < 4; ++n)
                acc[m][n] = __builtin_amdgcn_mfma_f32_16x16x32_f16(
                    a1f[m], b1f[n], acc[m][n], 0, 0, 0);
#pragma unroll
        for (int m = 0; m < 4; ++m)
#pragma unroll
            for (int n = 0; n < 4; ++n)
                accc[m][n] = __builtin_amdgcn_mfma_f32_16x16x32_f16(
                    a1f[m], b2f[n], accc[m][n], 0, 0, 0);
#pragma unroll
        for (int m = 0; m < 4; ++m)
#pragma unroll
            for (int n = 0; n < 4; ++n)
                accc[m][n] = __builtin_amdgcn_mfma_f32_16x16x32_f16(
                    a2f[m], b1f[n], accc[m][n], 0, 0, 0);
        __syncthreads();   // all reads done before next overwrite
    }

    // epilogue: C/D layout col=lane&15, row=(lane>>4)*4+reg  [m89/m91 verified]
    float bvals[4];
#pragma unroll
    for (int n = 0; n < 4; ++n) bvals[n] = bias[col0 + wc + n * 16 + lr];

    constexpr float INV4096 = 1.0f / 4096.0f;
#pragma unroll
    for (int m = 0; m < 4; ++m) {
#pragma unroll
        for (int jj = 0; jj < 4; ++jj) {
            const size_t grow = row0 + wr + m * 16 + lg * 4 + jj;
#pragma unroll
            for (int n = 0; n < 4; ++n) {
                const int gcol = col0 + wc + n * 16 + lr;
                float v = acc[m][n][jj] + accc[m][n][jj] * INV4096 + bvals[n];
                v = fmaxf(v, 0.f);
                if (EPI == 0) {
                    const ushort ha = f2h(v);
                    ((ushort*)Ca)[grow * N + gcol] = ha;
                    Cb[grow * N + gcol] = f2h((v - h2f(ha)) * 4096.f);
                } else {
                    ((float*)Ca)[grow * N + gcol] = v;
                }
            }
        }
    }
}

// ---------------------------------------------------------------------------
// bf16 MFMA GEMM (decoder): C = epi(A @ Bt^T + bias), Bt is [N][K] bf16.
// APATH 0: A is [M][K] bf16 via global_load_lds. APATH 1: A row m = CBb[idx[m]].
// EPI 0: relu -> bf16 out.  EPI 1: sigmoid -> fp32 out.  (round-2 proven)
// ---------------------------------------------------------------------------
template<int EPI, int APATH>
__global__ __launch_bounds__(256)
void gemm_mfma(const ushort* __restrict__ A, const ushort* __restrict__ CBb,
               const int* __restrict__ idx, const ushort* __restrict__ Bt,
               const float* __restrict__ bias, void* __restrict__ Cout,
               int M, int K, int N) {
    constexpr int BM = 128, BN = 128, BK = 32;
    __shared__ ushort As[BM][BK];
    __shared__ ushort Bs[BN][BK];

    const int hw = blockIdx.x;
    const int x  = hw & 7, j = hw >> 3;
    const int bc = j & 7, br = (j >> 3) * 8 + x;
    const int row0 = br * BM, col0 = bc * BN;

    const int tid  = threadIdx.x;
    const int lane = tid & 63, wid = tid >> 6;
    const int wr = (wid >> 1) * 64, wc = (wid & 1) * 64;
    const int lr = lane & 15, lg = lane >> 4;

    f32x4 acc[4][4] = {};

    const int r0 = tid >> 2;
    const int kq = (tid & 3) * 8;

    const ushort* Bg0 = Bt + (size_t)(col0 + r0) * K + kq;
    const ushort* Bg1 = Bt + (size_t)(col0 + 64 + r0) * K + kq;
    ushort* lA0 = &As[r0][kq];
    ushort* lA1 = &As[64 + r0][kq];
    ushort* lB0 = &Bs[r0][kq];
    ushort* lB1 = &Bs[64 + r0][kq];

    const ushort* Ag0;
    const ushort* Ag1;
    if (APATH == 0) {
        Ag0 = A + (size_t)(row0 + r0) * K + kq;
        Ag1 = A + (size_t)(row0 + 64 + r0) * K + kq;
    } else {
        Ag0 = CBb + (size_t)idx[row0 + r0] * K + kq;
        Ag1 = CBb + (size_t)idx[row0 + 64 + r0] * K + kq;
    }

    for (int k0 = 0; k0 < K; k0 += BK) {
        if (APATH == 0) {
            async_copy16(lA0, Ag0 + k0);
            async_copy16(lA1, Ag1 + k0);
            async_copy16(lB0, Bg0 + k0);
            async_copy16(lB1, Bg1 + k0);
        } else {
            const int4 ra0 = *(const int4*)(Ag0 + k0);
            const int4 ra1 = *(const int4*)(Ag1 + k0);
            async_copy16(lB0, Bg0 + k0);
            async_copy16(lB1, Bg1 + k0);
            *(int4*)lA0 = ra0;
            *(int4*)lA1 = ra1;
        }
        __syncthreads();

        bf16x8 av[4], bv[4];
#pragma unroll
        for (int m = 0; m < 4; ++m)
            av[m] = *(const bf16x8*)&As[wr + m * 16 + lr][lg * 8];
#pragma unroll
        for (int n = 0; n < 4; ++n)
            bv[n] = *(const bf16x8*)&Bs[wc + n * 16 + lr][lg * 8];
#pragma unroll
        for (int m = 0; m < 4; ++m)
#pragma unroll
            for (int n = 0; n < 4; ++n)
                acc[m][n] = __builtin_amdgcn_mfma_f32_16x16x32_bf16(
                    av[m], bv[n], acc[m][n], 0, 0, 0);
        __syncthreads();
    }

    float bvals[4];
#pragma unroll
    for (int n = 0; n < 4; ++n) bvals[n] = bias[col0 + wc + n * 16 + lr];

#pragma unroll
    for (int m = 0; m < 4; ++m) {
#pragma unroll
        for (int jj = 0; jj < 4; ++jj) {
            const size_t grow = row0 + wr + m * 16 + lg * 4 + jj;
#pragma unroll
            for (int n = 0; n < 4; ++n) {
                const int gcol = col0 + wc + n * 16 + lr;
                float v = acc[m][n][jj] + bvals[n];
                if (EPI == 0) {
                    v = fmaxf(v, 0.f);
                    ((ushort*)Cout)[grow * N + gcol] = f2bf(v);
                } else {
                    v = 1.0f / (1.0f + expf(-v));
                    ((float*)Cout)[grow * N + gcol] = v;
                }
            }
        }
    }
}

// ---------------------------------------------------------------------------
// Codebook stats + bf16 convert: S[i]=sum_j C[i,j], Q[i]=sum_j C[i,j]^2 (fp64).
// ---------------------------------------------------------------------------
__global__ __launch_bounds__(256)
void cb_stats(const float* __restrict__ CB, float* __restrict__ S,
              float* __restrict__ Q, ushort* __restrict__ CBb) {
    const int i = blockIdx.x;
    const float* row = CB + (size_t)i * DIM;
    double s = 0.0, q = 0.0;
    for (int j = threadIdx.x; j < DIM; j += 256) {
        const float fv = row[j];
        CBb[(size_t)i * DIM + j] = f2bf(fv);
        const double v = (double)fv;
        s += v;
        q += v * v;
    }
#pragma unroll
    for (int off = 32; off; off >>= 1) {
        s += __shfl_down(s, off);
        q += __shfl_down(q, off);
    }
    __shared__ double sS[4], sQ[4];
    const int wid = threadIdx.x >> 6;
    if ((threadIdx.x & 63) == 0) { sS[wid] = s; sQ[wid] = q; }
    __syncthreads();
    if (threadIdx.x == 0) {
        for (int w = 1; w < 4; ++w) { s += sS[w]; q += sQ[w]; }
        S[i] = (float)s;
        Q[i] = (float)q;
    }
}

// ---------------------------------------------------------------------------
// VQ argmin (numpy-exact fp32 op order, first-index tie-break) + fp32 gather.
// ---------------------------------------------------------------------------
__global__ __launch_bounds__(256)
void vq_argmin_gather(const float* __restrict__ z_e,
                      const float* __restrict__ S, const float* __restrict__ Q,
                      const float* __restrict__ CB, float* __restrict__ z_q,
                      int* __restrict__ idxp) {
    const int n = blockIdx.x;
    const float* z = z_e + (size_t)n * DIM;
    const int tid = threadIdx.x;

    float best = 3.4e38f;
    int   bi   = 0x7fffffff;
    for (int i = tid; i < DIM; i += 256) {
        const float zv = z[i];
        const float t  = __fmul_rn(zv, zv);
        const float a  = __fmul_rn(1024.0f, t);
        const float b  = __fmul_rn(__fmul_rn(2.0f, zv), S[i]);
        const float d  = __fadd_rn(__fsub_rn(a, b), Q[i]);
        if (d < best) { best = d; bi = i; }
    }
#pragma unroll
    for (int off = 32; off; off >>= 1) {
        const float od = __shfl_down(best, off);
        const int   oi = __shfl_down(bi,   off);
        if (od < best || (od == best && oi < bi)) { best = od; bi = oi; }
    }
    __shared__ float sd[4];
    __shared__ int   si[4];
    const int wid = tid >> 6;
    if ((tid & 63) == 0) { sd[wid] = best; si[wid] = bi; }
    __syncthreads();
    if (tid == 0) {
        for (int w = 1; w < 4; ++w)
            if (sd[w] < best || (sd[w] == best && si[w] < bi)) { best = sd[w]; bi = si[w]; }
        si[0] = bi;
    }
    __syncthreads();
    bi = si[0];
    if (tid == 0) idxp[n] = bi;

    const float4* src = (const float4*)(CB + (size_t)bi * DIM);
    float4* dst = (float4*)(z_q + (size_t)n * DIM);
    dst[tid] = src[tid];
}

// ---------------------------------------------------------------------------
extern "C" void kernel_launch(void* const* d_in, const int* in_sizes, int n_in,
                              void* d_out, int out_size, void* d_ws, size_t ws_size,
                              hipStream_t stream) {
    const float* x  = (const float*)d_in[0];
    const float* W1 = (const float*)d_in[1];
    const float* b1 = (const float*)d_in[2];
    const float* W2 = (const float*)d_in[3];
    const float* b2 = (const float*)d_in[4];
    const float* CB = (const float*)d_in[5];
    const float* W3 = (const float*)d_in[6];
    const float* b3 = (const float*)d_in[7];
    const float* W4 = (const float*)d_in[8];
    const float* b4 = (const float*)d_in[9];

    float* out     = (float*)d_out;
    float* x_recon = out;                              // written once by GEMM4
    float* z_e     = out + (size_t)NROWS * DIM;        // written once by enc2 (2 halves)
    float* z_q     = out + (size_t)2 * NROWS * DIM;    // written once by VQ

    // NO scratch in d_out this round (round-3 post-timing failure isolated to
    // the d_out-overlay; rounds 1-2 with ws-only scratch passed replay).
    // ws layout (bytes), high-water 80 MB < proven 134 MB:
    //   0         W1ta | 2097152 W1tb | 4194304 W2ta | 6291456 W2tb   (fp16, 2 MB each)
    //   8388608   W3t  | 10485760 W4t | 12582912 CBb                  (bf16, 2 MB each)
    //   14680064  S (4 KB) | 14684160 Q (4 KB) | 14688256 idx (128 KB)
    //   16777216  h1a half (32 MB) | 50331648 h1b half (32 MB)
    //   16777216  h3 bf16 (64 MB)  -- reuses h1 region after encoder done
    char* wsb = (char*)d_ws;
    ushort* W1ta = (ushort*)(wsb);
    ushort* W1tb = (ushort*)(wsb + 2097152);
    ushort* W2ta = (ushort*)(wsb + 4194304);
    ushort* W2tb = (ushort*)(wsb + 6291456);
    ushort* W3t  = (ushort*)(wsb + 8388608);
    ushort* W4t  = (ushort*)(wsb + 10485760);
    ushort* CBb  = (ushort*)(wsb + 12582912);
    float*  S    = (float*)(wsb + 14680064);
    float*  Q    = (float*)(wsb + 14684160);
    int*    idx  = (int*)(wsb + 14688256);
    ushort* h1a  = (ushort*)(wsb + 16777216);
    ushort* h1b  = (ushort*)(wsb + 50331648);
    ushort* h3b  = (ushort*)(wsb + 16777216);   // overlaps h1 (h1 dead by then)

    const dim3 blk(256);
    const dim3 grid_half((HALF / 128) * (DIM / 128));    // 1024 (128%8==0: bijective swizzle)
    const dim3 grid_full((NROWS / 128) * (DIM / 128));   // 2048
    const dim3 grid_tr(32, 32);

    // prep
    split_wt<<<grid_tr, blk, 0, stream>>>(W1, W1ta, W1tb);
    split_wt<<<grid_tr, blk, 0, stream>>>(W2, W2ta, W2tb);
    wt_convert<<<grid_tr, blk, 0, stream>>>(W3, W3t);
    wt_convert<<<grid_tr, blk, 0, stream>>>(W4, W4t);
    cb_stats<<<dim3(DIM), blk, 0, stream>>>(CB, S, Q, CBb);

    // encoder (fp16x2 split MFMA, fp32-accurate), two half-batches so the
    // h1 fp16 pair fits in ws
    for (int h = 0; h < 2; ++h) {
        const size_t ro = (size_t)h * HALF * DIM;
        gemm_f16x2<0, 0><<<grid_half, blk, 0, stream>>>(
            x + ro, (const ushort*)nullptr, (const ushort*)nullptr,
            W1ta, W1tb, b1, (void*)h1a, h1b, HALF, DIM, DIM);
        gemm_f16x2<1, 1><<<grid_half, blk, 0, stream>>>(
            (const float*)nullptr, h1a, h1b,
            W2ta, W2tb, b2, (void*)(z_e + ro), (ushort*)nullptr, HALF, DIM, DIM);
    }

    // VQ
    vq_argmin_gather<<<dim3(NROWS), blk, 0, stream>>>(z_e, S, Q, CB, z_q, idx);

    // decoder (bf16 MFMA)
    gemm_mfma<0, 1><<<grid_full, blk, 0, stream>>>(
        (const ushort*)nullptr, CBb, idx, W3t, b3, (void*)h3b, NROWS, DIM, DIM);
    gemm_mfma<1, 0><<<grid_full, blk, 0, stream>>>(
        h3b, (const ushort*)nullptr, (const int*)nullptr, W4t, b4, (void*)x_recon,
        NROWS, DIM, DIM);
}

// Round 5
// 1168.827 us; speedup vs baseline: 2.7937x; 1.3179x over previous
//
#include <hip/hip_runtime.h>
#include <hip/hip_bf16.h>
#include <math.h>

// Problem constants (fixed by the reference)
#define NROWS 32768
#define HALF  16384
#define DIM   1024      // D == H == K == 1024

typedef __attribute__((ext_vector_type(8))) short bf16x8;     // 8 bf16 (4 VGPRs)
typedef _Float16 f16x8 __attribute__((ext_vector_type(8)));   // 8 fp16 (4 VGPRs)
typedef __attribute__((ext_vector_type(4))) float f32x4;      // MFMA accumulator

__device__ __forceinline__ ushort f2bf(float f) {
    union { float f; unsigned u; } a; a.f = f;
    unsigned r = a.u + 0x7fff + ((a.u >> 16) & 1);   // RNE
    return (ushort)(r >> 16);
}
__device__ __forceinline__ ushort f2h(float f) {
    union { _Float16 h; ushort u; } c; c.h = (_Float16)f; return c.u;
}
__device__ __forceinline__ float h2f(ushort u) {
    union { ushort u; _Float16 h; } c; c.u = u; return (float)c.h;
}

__device__ __forceinline__ void async_copy16(void* lds, const void* g) {
    __builtin_amdgcn_global_load_lds(
        (const __attribute__((address_space(1))) void*)g,
        (__attribute__((address_space(3))) void*)lds,
        16, 0, 0);
}

// split 8 fp32 -> fp16 main + fp16 residual*4096
__device__ __forceinline__ void split8(const float4 lo, const float4 hi,
                                       f16x8& a, f16x8& b) {
    const float v[8] = {lo.x, lo.y, lo.z, lo.w, hi.x, hi.y, hi.z, hi.w};
#pragma unroll
    for (int i = 0; i < 8; ++i) {
        const _Float16 ha = (_Float16)v[i];
        a[i] = ha;
        b[i] = (_Float16)((v[i] - (float)ha) * 4096.f);
    }
}

// ---------------------------------------------------------------------------
// Transpose + fp16x2 split: Wta[n][k] = f16(W[k][n]), Wtb = f16(resid*4096).
// ---------------------------------------------------------------------------
__global__ __launch_bounds__(256)
void split_wt(const float* __restrict__ W, ushort* __restrict__ Wta,
              ushort* __restrict__ Wtb) {
    __shared__ float t[32][33];
    const int bi = blockIdx.y;   // k block
    const int bj = blockIdx.x;   // n block
    const int tx = threadIdx.x & 31, ty = threadIdx.x >> 5;   // 32 x 8
#pragma unroll
    for (int r = 0; r < 4; ++r)
        t[ty + r * 8][tx] = W[(size_t)(bi * 32 + ty + r * 8) * DIM + bj * 32 + tx];
    __syncthreads();
#pragma unroll
    for (int r = 0; r < 4; ++r) {
        const float v = t[tx][ty + r * 8];
        const ushort a = f2h(v);
        const size_t o = (size_t)(bj * 32 + ty + r * 8) * DIM + bi * 32 + tx;
        Wta[o] = a;
        Wtb[o] = f2h((v - h2f(a)) * 4096.f);
    }
}

// ---------------------------------------------------------------------------
// Transpose + convert to bf16 (decoder weights): Wt[n][k] = bf16(W[k][n]).
// ---------------------------------------------------------------------------
__global__ __launch_bounds__(256)
void wt_convert(const float* __restrict__ W, ushort* __restrict__ Wt) {
    __shared__ float t[32][33];
    const int bi = blockIdx.y;
    const int bj = blockIdx.x;
    const int tx = threadIdx.x & 31, ty = threadIdx.x >> 5;
#pragma unroll
    for (int r = 0; r < 4; ++r)
        t[ty + r * 8][tx] = W[(size_t)(bi * 32 + ty + r * 8) * DIM + bj * 32 + tx];
    __syncthreads();
#pragma unroll
    for (int r = 0; r < 4; ++r)
        Wt[(size_t)(bj * 32 + ty + r * 8) * DIM + bi * 32 + tx] = f2bf(t[tx][ty + r * 8]);
}

// ---------------------------------------------------------------------------
// fp16x2 split MFMA GEMM (encoder): C = relu(A @ Bt^T + bias), fp32-accurate.
// A = Aa + Ab/4096, B = Ba + Bb/4096 ([N][K] fp16 pairs in ws).
// acc += Aa*Ba ; accc += Aa*Bb + Ab*Ba ; C = acc + accc/4096 + bias.
// ROUND-5 GEOMETRY: block tile 128x64, BK=32, 4 waves (2x2), wave tile 64x32
// (4x2 16x16x32 frags). Halves acc regs (64) vs round-4's 64x64 wave tile
// (128) -> combined VGPR+AGPR ~150 -> 3 waves/SIMD (was 1, Occupancy 11.6%).
// APATH 0: A is fp32 [M][K] (d_in), split in-register during staging.
// APATH 1: A is fp16 pair [M][K] (ws), staged via global_load_lds.
// EPI 0: relu -> fp16 pair out.  EPI 1: relu -> fp32 out.
// ---------------------------------------------------------------------------
template<int APATH, int EPI>
__global__ __launch_bounds__(256, 3)
void gemm_f16x2(const float* __restrict__ Af,
                const ushort* __restrict__ Aa, const ushort* __restrict__ Ab,
                const ushort* __restrict__ Ba, const ushort* __restrict__ Bb,
                const float* __restrict__ bias, void* __restrict__ Ca,
                ushort* __restrict__ Cb, int M, int K, int N) {
    constexpr int BM = 128, BN = 64, BK = 32;
    __shared__ ushort Asa[BM][BK];
    __shared__ ushort Asb[BM][BK];
    __shared__ ushort Bsa[BN][BK];
    __shared__ ushort Bsb[BN][BK];

    // XCD-aware swizzle: 16 col-blocks share one A row-panel; keep them on one
    // XCD back-to-back. Bijective: gridDim = 8 * 16 * (M/128 / 8), M/128 % 8 == 0.
    const int hw = blockIdx.x;
    const int x  = hw & 7, j = hw >> 3;
    const int bc = j & 15, br = (j >> 4) * 8 + x;
    const int row0 = br * BM, col0 = bc * BN;

    const int tid  = threadIdx.x;
    const int lane = tid & 63, wid = tid >> 6;
    const int wr = (wid >> 1) * 64, wc = (wid & 1) * 32;   // wave tile 64x32
    const int lr = lane & 15, lg = lane >> 4;

    f32x4 acc[4][2]  = {};
    f32x4 accc[4][2] = {};

    const int r0 = tid >> 2;           // 0..63
    const int kq = (tid & 3) * 8;      // k-element offset: 0,8,16,24

    // B operands: 64 rows x 4 k-chunks = 256 chunks = 1 per thread per buffer
    const ushort* Bga = Ba + (size_t)(col0 + r0) * K + kq;
    const ushort* Bgb = Bb + (size_t)(col0 + r0) * K + kq;
    ushort* lBa = &Bsa[r0][kq];
    ushort* lBb = &Bsb[r0][kq];

    // A operands: 128 rows -> chunks at r0 and r0+64
    const float*  Af0 = nullptr; const float*  Af1 = nullptr;
    const ushort* Aga0 = nullptr; const ushort* Aga1 = nullptr;
    const ushort* Agb0 = nullptr; const ushort* Agb1 = nullptr;
    if (APATH == 0) {
        Af0 = Af + (size_t)(row0 + r0) * K + kq;
        Af1 = Af + (size_t)(row0 + 64 + r0) * K + kq;
    } else {
        Aga0 = Aa + (size_t)(row0 + r0) * K + kq;
        Aga1 = Aa + (size_t)(row0 + 64 + r0) * K + kq;
        Agb0 = Ab + (size_t)(row0 + r0) * K + kq;
        Agb1 = Ab + (size_t)(row0 + 64 + r0) * K + kq;
    }
    ushort* lAa0 = &Asa[r0][kq];      ushort* lAa1 = &Asa[64 + r0][kq];
    ushort* lAb0 = &Asb[r0][kq];      ushort* lAb1 = &Asb[64 + r0][kq];

    for (int k0 = 0; k0 < K; k0 += BK) {
        if (APATH == 0) {
            // fp32 loads first (latency), then async B copies, then split+ds_write
            const float4 f00 = *(const float4*)(Af0 + k0);
            const float4 f01 = *(const float4*)(Af0 + k0 + 4);
            const float4 f10 = *(const float4*)(Af1 + k0);
            const float4 f11 = *(const float4*)(Af1 + k0 + 4);
            async_copy16(lBa, Bga + k0);
            async_copy16(lBb, Bgb + k0);
            f16x8 a0, b0, a1, b1;
            split8(f00, f01, a0, b0);
            split8(f10, f11, a1, b1);
            *(f16x8*)lAa0 = a0;
            *(f16x8*)lAb0 = b0;
            *(f16x8*)lAa1 = a1;
            *(f16x8*)lAb1 = b1;
        } else {
            async_copy16(lAa0, Aga0 + k0);
            async_copy16(lAa1, Aga1 + k0);
            async_copy16(lAb0, Agb0 + k0);
            async_copy16(lAb1, Agb1 + k0);
            async_copy16(lBa, Bga + k0);
            async_copy16(lBb, Bgb + k0);
        }
        __syncthreads();   // drains vmcnt+lgkm; tiles visible to all waves

        f16x8 a1f[4], a2f[4], b1f[2], b2f[2];
#pragma unroll
        for (int m = 0; m < 4; ++m) {
            a1f[m] = *(const f16x8*)&Asa[wr + m * 16 + lr][lg * 8];
            a2f[m] = *(const f16x8*)&Asb[wr + m * 16 + lr][lg * 8];
        }
#pragma unroll
        for (int n = 0; n < 2; ++n) {
            b1f[n] = *(const f16x8*)&Bsa[wc + n * 16 + lr][lg * 8];
            b2f[n] = *(const f16x8*)&Bsb[wc + n * 16 + lr][lg * 8];
        }
#pragma unroll
        for (int m = 0; m < 4; ++m)
#pragma unroll
            for (int n = 0; n < 2; ++n)
                acc[m][n] = __builtin_amdgcn_mfma_f32_16x16x32_f16(
                    a1f[m], b1f[n], acc[m][n], 0, 0, 0);
#pragma unroll
        for (int m = 0; m < 4; ++m)
#pragma unroll
            for (int n = 0; n < 2; ++n)
                accc[m][n] = __builtin_amdgcn_mfma_f32_16x16x32_f16(
                    a1f[m], b2f[n], accc[m][n], 0, 0, 0);
#pragma unroll
        for (int m = 0; m < 4; ++m)
#pragma unroll
            for (int n = 0; n < 2; ++n)
                accc[m][n] = __builtin_amdgcn_mfma_f32_16x16x32_f16(
                    a2f[m], b1f[n], accc[m][n], 0, 0, 0);
        __syncthreads();   // all reads done before next overwrite
    }

    // epilogue: C/D layout col=lane&15, row=(lane>>4)*4+reg  [m89/m91 verified]
    float bvals[2];
#pragma unroll
    for (int n = 0; n < 2; ++n) bvals[n] = bias[col0 + wc + n * 16 + lr];

    constexpr float INV4096 = 1.0f / 4096.0f;
#pragma unroll
    for (int m = 0; m < 4; ++m) {
#pragma unroll
        for (int jj = 0; jj < 4; ++jj) {
            const size_t grow = row0 + wr + m * 16 + lg * 4 + jj;
#pragma unroll
            for (int n = 0; n < 2; ++n) {
                const int gcol = col0 + wc + n * 16 + lr;
                float v = acc[m][n][jj] + accc[m][n][jj] * INV4096 + bvals[n];
                v = fmaxf(v, 0.f);
                if (EPI == 0) {
                    const ushort ha = f2h(v);
                    ((ushort*)Ca)[grow * N + gcol] = ha;
                    Cb[grow * N + gcol] = f2h((v - h2f(ha)) * 4096.f);
                } else {
                    ((float*)Ca)[grow * N + gcol] = v;
                }
            }
        }
    }
}

// ---------------------------------------------------------------------------
// bf16 MFMA GEMM (decoder): C = epi(A @ Bt^T + bias), Bt is [N][K] bf16.
// APATH 0: A is [M][K] bf16 via global_load_lds. APATH 1: A row m = CBb[idx[m]].
// EPI 0: relu -> bf16 out.  EPI 1: sigmoid -> fp32 out.  (round-2 proven)
// ---------------------------------------------------------------------------
template<int EPI, int APATH>
__global__ __launch_bounds__(256)
void gemm_mfma(const ushort* __restrict__ A, const ushort* __restrict__ CBb,
               const int* __restrict__ idx, const ushort* __restrict__ Bt,
               const float* __restrict__ bias, void* __restrict__ Cout,
               int M, int K, int N) {
    constexpr int BM = 128, BN = 128, BK = 32;
    __shared__ ushort As[BM][BK];
    __shared__ ushort Bs[BN][BK];

    const int hw = blockIdx.x;
    const int x  = hw & 7, j = hw >> 3;
    const int bc = j & 7, br = (j >> 3) * 8 + x;
    const int row0 = br * BM, col0 = bc * BN;

    const int tid  = threadIdx.x;
    const int lane = tid & 63, wid = tid >> 6;
    const int wr = (wid >> 1) * 64, wc = (wid & 1) * 64;
    const int lr = lane & 15, lg = lane >> 4;

    f32x4 acc[4][4] = {};

    const int r0 = tid >> 2;
    const int kq = (tid & 3) * 8;

    const ushort* Bg0 = Bt + (size_t)(col0 + r0) * K + kq;
    const ushort* Bg1 = Bt + (size_t)(col0 + 64 + r0) * K + kq;
    ushort* lA0 = &As[r0][kq];
    ushort* lA1 = &As[64 + r0][kq];
    ushort* lB0 = &Bs[r0][kq];
    ushort* lB1 = &Bs[64 + r0][kq];

    const ushort* Ag0;
    const ushort* Ag1;
    if (APATH == 0) {
        Ag0 = A + (size_t)(row0 + r0) * K + kq;
        Ag1 = A + (size_t)(row0 + 64 + r0) * K + kq;
    } else {
        Ag0 = CBb + (size_t)idx[row0 + r0] * K + kq;
        Ag1 = CBb + (size_t)idx[row0 + 64 + r0] * K + kq;
    }

    for (int k0 = 0; k0 < K; k0 += BK) {
        if (APATH == 0) {
            async_copy16(lA0, Ag0 + k0);
            async_copy16(lA1, Ag1 + k0);
            async_copy16(lB0, Bg0 + k0);
            async_copy16(lB1, Bg1 + k0);
        } else {
            const int4 ra0 = *(const int4*)(Ag0 + k0);
            const int4 ra1 = *(const int4*)(Ag1 + k0);
            async_copy16(lB0, Bg0 + k0);
            async_copy16(lB1, Bg1 + k0);
            *(int4*)lA0 = ra0;
            *(int4*)lA1 = ra1;
        }
        __syncthreads();

        bf16x8 av[4], bv[4];
#pragma unroll
        for (int m = 0; m < 4; ++m)
            av[m] = *(const bf16x8*)&As[wr + m * 16 + lr][lg * 8];
#pragma unroll
        for (int n = 0; n < 4; ++n)
            bv[n] = *(const bf16x8*)&Bs[wc + n * 16 + lr][lg * 8];
#pragma unroll
        for (int m = 0; m < 4; ++m)
#pragma unroll
            for (int n = 0; n < 4; ++n)
                acc[m][n] = __builtin_amdgcn_mfma_f32_16x16x32_bf16(
                    av[m], bv[n], acc[m][n], 0, 0, 0);
        __syncthreads();
    }

    float bvals[4];
#pragma unroll
    for (int n = 0; n < 4; ++n) bvals[n] = bias[col0 + wc + n * 16 + lr];

#pragma unroll
    for (int m = 0; m < 4; ++m) {
#pragma unroll
        for (int jj = 0; jj < 4; ++jj) {
            const size_t grow = row0 + wr + m * 16 + lg * 4 + jj;
#pragma unroll
            for (int n = 0; n < 4; ++n) {
                const int gcol = col0 + wc + n * 16 + lr;
                float v = acc[m][n][jj] + bvals[n];
                if (EPI == 0) {
                    v = fmaxf(v, 0.f);
                    ((ushort*)Cout)[grow * N + gcol] = f2bf(v);
                } else {
                    v = 1.0f / (1.0f + expf(-v));
                    ((float*)Cout)[grow * N + gcol] = v;
                }
            }
        }
    }
}

// ---------------------------------------------------------------------------
// Codebook stats + bf16 convert: S[i]=sum_j C[i,j], Q[i]=sum_j C[i,j]^2 (fp64).
// ---------------------------------------------------------------------------
__global__ __launch_bounds__(256)
void cb_stats(const float* __restrict__ CB, float* __restrict__ S,
              float* __restrict__ Q, ushort* __restrict__ CBb) {
    const int i = blockIdx.x;
    const float* row = CB + (size_t)i * DIM;
    double s = 0.0, q = 0.0;
    for (int j = threadIdx.x; j < DIM; j += 256) {
        const float fv = row[j];
        CBb[(size_t)i * DIM + j] = f2bf(fv);
        const double v = (double)fv;
        s += v;
        q += v * v;
    }
#pragma unroll
    for (int off = 32; off; off >>= 1) {
        s += __shfl_down(s, off);
        q += __shfl_down(q, off);
    }
    __shared__ double sS[4], sQ[4];
    const int wid = threadIdx.x >> 6;
    if ((threadIdx.x & 63) == 0) { sS[wid] = s; sQ[wid] = q; }
    __syncthreads();
    if (threadIdx.x == 0) {
        for (int w = 1; w < 4; ++w) { s += sS[w]; q += sQ[w]; }
        S[i] = (float)s;
        Q[i] = (float)q;
    }
}

// ---------------------------------------------------------------------------
// VQ argmin (numpy-exact fp32 op order, first-index tie-break) + fp32 gather.
// ---------------------------------------------------------------------------
__global__ __launch_bounds__(256)
void vq_argmin_gather(const float* __restrict__ z_e,
                      const float* __restrict__ S, const float* __restrict__ Q,
                      const float* __restrict__ CB, float* __restrict__ z_q,
                      int* __restrict__ idxp) {
    const int n = blockIdx.x;
    const float* z = z_e + (size_t)n * DIM;
    const int tid = threadIdx.x;

    float best = 3.4e38f;
    int   bi   = 0x7fffffff;
    for (int i = tid; i < DIM; i += 256) {
        const float zv = z[i];
        const float t  = __fmul_rn(zv, zv);
        const float a  = __fmul_rn(1024.0f, t);
        const float b  = __fmul_rn(__fmul_rn(2.0f, zv), S[i]);
        const float d  = __fadd_rn(__fsub_rn(a, b), Q[i]);
        if (d < best) { best = d; bi = i; }
    }
#pragma unroll
    for (int off = 32; off; off >>= 1) {
        const float od = __shfl_down(best, off);
        const int   oi = __shfl_down(bi,   off);
        if (od < best || (od == best && oi < bi)) { best = od; bi = oi; }
    }
    __shared__ float sd[4];
    __shared__ int   si[4];
    const int wid = tid >> 6;
    if ((tid & 63) == 0) { sd[wid] = best; si[wid] = bi; }
    __syncthreads();
    if (tid == 0) {
        for (int w = 1; w < 4; ++w)
            if (sd[w] < best || (sd[w] == best && si[w] < bi)) { best = sd[w]; bi = si[w]; }
        si[0] = bi;
    }
    __syncthreads();
    bi = si[0];
    if (tid == 0) idxp[n] = bi;

    const float4* src = (const float4*)(CB + (size_t)bi * DIM);
    float4* dst = (float4*)(z_q + (size_t)n * DIM);
    dst[tid] = src[tid];
}

// ---------------------------------------------------------------------------
extern "C" void kernel_launch(void* const* d_in, const int* in_sizes, int n_in,
                              void* d_out, int out_size, void* d_ws, size_t ws_size,
                              hipStream_t stream) {
    const float* x  = (const float*)d_in[0];
    const float* W1 = (const float*)d_in[1];
    const float* b1 = (const float*)d_in[2];
    const float* W2 = (const float*)d_in[3];
    const float* b2 = (const float*)d_in[4];
    const float* CB = (const float*)d_in[5];
    const float* W3 = (const float*)d_in[6];
    const float* b3 = (const float*)d_in[7];
    const float* W4 = (const float*)d_in[8];
    const float* b4 = (const float*)d_in[9];

    float* out     = (float*)d_out;
    float* x_recon = out;                              // written once by GEMM4
    float* z_e     = out + (size_t)NROWS * DIM;        // written once by enc2 (2 halves)
    float* z_q     = out + (size_t)2 * NROWS * DIM;    // written once by VQ

    // ws layout (bytes), high-water 80 MB (ws-only scratch; d_out written once
    // per region -- round-3's d_out-overlay replay failure must not recur):
    //   0         W1ta | 2097152 W1tb | 4194304 W2ta | 6291456 W2tb   (fp16, 2 MB each)
    //   8388608   W3t  | 10485760 W4t | 12582912 CBb                  (bf16, 2 MB each)
    //   14680064  S (4 KB) | 14684160 Q (4 KB) | 14688256 idx (128 KB)
    //   16777216  h1a half (32 MB) | 50331648 h1b half (32 MB)
    //   16777216  h3 bf16 (64 MB)  -- reuses h1 region after encoder done
    char* wsb = (char*)d_ws;
    ushort* W1ta = (ushort*)(wsb);
    ushort* W1tb = (ushort*)(wsb + 2097152);
    ushort* W2ta = (ushort*)(wsb + 4194304);
    ushort* W2tb = (ushort*)(wsb + 6291456);
    ushort* W3t  = (ushort*)(wsb + 8388608);
    ushort* W4t  = (ushort*)(wsb + 10485760);
    ushort* CBb  = (ushort*)(wsb + 12582912);
    float*  S    = (float*)(wsb + 14680064);
    float*  Q    = (float*)(wsb + 14684160);
    int*    idx  = (int*)(wsb + 14688256);
    ushort* h1a  = (ushort*)(wsb + 16777216);
    ushort* h1b  = (ushort*)(wsb + 50331648);
    ushort* h3b  = (ushort*)(wsb + 16777216);   // overlaps h1 (h1 dead by then)

    const dim3 blk(256);
    const dim3 grid_enc((HALF / 128) * (DIM / 64));      // 2048 (128%8==0: bijective swizzle)
    const dim3 grid_full((NROWS / 128) * (DIM / 128));   // 2048
    const dim3 grid_tr(32, 32);

    // prep
    split_wt<<<grid_tr, blk, 0, stream>>>(W1, W1ta, W1tb);
    split_wt<<<grid_tr, blk, 0, stream>>>(W2, W2ta, W2tb);
    wt_convert<<<grid_tr, blk, 0, stream>>>(W3, W3t);
    wt_convert<<<grid_tr, blk, 0, stream>>>(W4, W4t);
    cb_stats<<<dim3(DIM), blk, 0, stream>>>(CB, S, Q, CBb);

    // encoder (fp16x2 split MFMA, fp32-accurate), two half-batches so the
    // h1 fp16 pair fits in ws
    for (int h = 0; h < 2; ++h) {
        const size_t ro = (size_t)h * HALF * DIM;
        gemm_f16x2<0, 0><<<grid_enc, blk, 0, stream>>>(
            x + ro, (const ushort*)nullptr, (const ushort*)nullptr,
            W1ta, W1tb, b1, (void*)h1a, h1b, HALF, DIM, DIM);
        gemm_f16x2<1, 1><<<grid_enc, blk, 0, stream>>>(
            (const float*)nullptr, h1a, h1b,
            W2ta, W2tb, b2, (void*)(z_e + ro), (ushort*)nullptr, HALF, DIM, DIM);
    }

    // VQ
    vq_argmin_gather<<<dim3(NROWS), blk, 0, stream>>>(z_e, S, Q, CB, z_q, idx);

    // decoder (bf16 MFMA)
    gemm_mfma<0, 1><<<grid_full, blk, 0, stream>>>(
        (const ushort*)nullptr, CBb, idx, W3t, b3, (void*)h3b, NROWS, DIM, DIM);
    gemm_mfma<1, 0><<<grid_full, blk, 0, stream>>>(
        h3b, (const ushort*)nullptr, (const int*)nullptr, W4t, b4, (void*)x_recon,
        NROWS, DIM, DIM);
}